// Round 11
// baseline (288.328 us; speedup 1.0000x reference)
//
#include <hip/hip_runtime.h>
#include <hip/hip_cooperative_groups.h>
#include <stdint.h>
#include <math.h>

namespace cg = cooperative_groups;

// Problem constants (match reference)
#define B_N   32768
#define INDIM 256
#define HID   256
#define NE    8
#define KM1   4
#define KCLS  5
#define BM    64
#define CAP   8192
#define GRID  512
#define SPB   64            // samples per block in phases A/B
#define NBLK_FB ((B_N + NE * BM) / BM)   // 520 fallback GEMM blocks

typedef __bf16 bf16x8 __attribute__((ext_vector_type(8)));
typedef float  f32x4  __attribute__((ext_vector_type(4)));
typedef unsigned short u16x8 __attribute__((ext_vector_type(8)));

__device__ __forceinline__ unsigned short f2bf(float f) {
    union { float f; unsigned u; } v; v.f = f;
    unsigned r = v.u + 0x7FFFu + ((v.u >> 16) & 1u);   // RNE
    return (unsigned short)(r >> 16);
}
__device__ __forceinline__ float bf2f(unsigned short b) {
    union { unsigned u; float f; } v; v.u = ((unsigned)b) << 16;
    return v.f;
}
// chunk-of-8-bf16 swizzle (bank-verified): slot = chunk ^ (row&7)
__device__ __forceinline__ int SWZ(int r, int c) { return c ^ (r & 7); }

__device__ __forceinline__ void gload_lds16(const void* g, void* l) {
    __builtin_amdgcn_global_load_lds(
        (__attribute__((address_space(1))) unsigned int*)(g),
        (__attribute__((address_space(3))) unsigned int*)(l),
        16, 0, 0);
}

// ======================= cooperative single kernel =======================
struct SMemA { float tile[64][65]; };                         // 16640 B
struct SMemB { int pp[GRID * NE]; int pr[32][NE][2];
               int pre8[NE]; int tot8[NE]; int posbuf[SPB]; };  // ~18.9 KB
struct SMemC { unsigned short xs[BM * 256]; float w2s[1040]; }; // 36928 B
union SMem { SMemA a; SMemB b; SMemC c; };

__global__ __launch_bounds__(256, 2) void k_all(
    const float* __restrict__ x, const int* __restrict__ sid,
    const float* __restrict__ W1, const float* __restrict__ b1,
    const float* __restrict__ W2, const float* __restrict__ b2,
    unsigned short* __restrict__ w1p, unsigned short* __restrict__ xb,
    int* __restrict__ perm, int* __restrict__ wpart,
    float* __restrict__ out)
{
    __shared__ SMem sm;
    cg::grid_group gg = cg::this_grid();
    int t = threadIdx.x, blk = blockIdx.x;
    int lane = t & 63, wave = t >> 6;
    int r15 = lane & 15, hi = lane >> 4;

    // ===== Phase A: per-block 64-sample histogram + W1 pack (blocks<128) ====
    int mye = -1;
    if (t < SPB) mye = sid[blk * SPB + t];
    if (wave == 0) {
        #pragma unroll
        for (int t2 = 0; t2 < NE; ++t2) {
            unsigned long long m = __ballot(mye == t2);
            if (lane == t2) wpart[blk * NE + t2] = (int)__popcll(m);
        }
    }
    if (blk < 128) {
        int e = blk >> 4, ti = (blk >> 2) & 3, th = blk & 3;
        const float* src = W1 + (((size_t)e * INDIM) + (size_t)ti * 64) * HID + th * 64;
        int col = t & 63, r0 = (t >> 6) * 16;
        #pragma unroll
        for (int rr = 0; rr < 16; ++rr)
            sm.a.tile[r0 + rr][col] = src[(size_t)(r0 + rr) * HID + col];
        __syncthreads();
        int u = t >> 6;
        #pragma unroll
        for (int ks2 = 0; ks2 < 2; ++ks2) {
            int ks = ti * 2 + ks2, nb = th * 4 + u;
            u16x8 v;
            #pragma unroll
            for (int j = 0; j < 8; ++j)
                v[j] = f2bf(sm.a.tile[ks2 * 32 + (lane >> 4) * 8 + j][u * 16 + (lane & 15)]);
            *(u16x8*)&w1p[((((size_t)e * 8 + ks) * 16 + nb) * 64 + lane) * 8] = v;
        }
    }
    __threadfence();
    gg.sync();

    // ===== Phase B: prefix + rank + convert/scatter x -> xb =====
    {   // coalesced load of all 512x8 partials into LDS (1024 int4)
        const int4* g4 = (const int4*)wpart;
        int4* l4 = (int4*)sm.b.pp;
        #pragma unroll
        for (int i = 0; i < 4; ++i) l4[i * 256 + t] = g4[i * 256 + t];
    }
    __syncthreads();
    {   // stage 1: thread t -> expert t&7, range t>>3 (16 chunks each)
        int e2 = t & 7, r = t >> 3;
        int sb = 0, sa = 0;
        #pragma unroll
        for (int c = 0; c < 16; ++c) {
            int ch = r * 16 + c;
            int v  = sm.b.pp[ch * 8 + e2];
            sa += v; sb += (ch < blk) ? v : 0;
        }
        sm.b.pr[r][e2][0] = sb; sm.b.pr[r][e2][1] = sa;
    }
    __syncthreads();
    if (t < NE) {
        int sb = 0, sa = 0;
        #pragma unroll
        for (int r = 0; r < 32; ++r) { sb += sm.b.pr[r][t][0]; sa += sm.b.pr[r][t][1]; }
        sm.b.pre8[t] = sb; sm.b.tot8[t] = sa;
    }
    __syncthreads();
    // carry counts across the LDS union in registers
    int c0 = sm.b.tot8[0], c1 = sm.b.tot8[1], c2 = sm.b.tot8[2], c3 = sm.b.tot8[3];
    int c4 = sm.b.tot8[4], c5 = sm.b.tot8[5], c6 = sm.b.tot8[6], c7 = sm.b.tot8[7];

    if (wave == 0) {   // rank own 64 samples (full wave)
        int posw = 0;
        #pragma unroll
        for (int t2 = 0; t2 < NE; ++t2) {
            unsigned long long m = __ballot(mye == t2);
            if (mye == t2) posw = (int)__popcll(m & ((1ull << lane) - 1ull));
        }
        int rank = sm.b.pre8[mye] + posw;
        int pos  = mye * CAP + rank;
        sm.b.posbuf[t] = pos;
        perm[pos] = blk * SPB + t;
    }
    __syncthreads();
    {   // convert 64 rows -> xb (pre-swizzled bf16); 4 threads/row, 64 floats each
        int row = t >> 2, seg = t & 3;
        int pos = sm.b.posbuf[row];
        int r   = pos & (BM - 1);
        const float* xr = x + (size_t)(blk * SPB + row) * INDIM + seg * 64;
        unsigned short* dst = xb + (size_t)pos * 256;
        #pragma unroll
        for (int cc = 0; cc < 8; ++cc) {
            int ch = seg * 8 + cc;
            f32x4 a0 = *(const f32x4*)(xr + cc * 8);
            f32x4 a1 = *(const f32x4*)(xr + cc * 8 + 4);
            u16x8 v;
            v[0] = f2bf(a0[0]); v[1] = f2bf(a0[1]); v[2] = f2bf(a0[2]); v[3] = f2bf(a0[3]);
            v[4] = f2bf(a1[0]); v[5] = f2bf(a1[1]); v[6] = f2bf(a1[2]); v[7] = f2bf(a1[3]);
            *(u16x8*)&dst[SWZ(r, ch) * 8] = v;
        }
    }
    __threadfence();
    gg.sync();

    // ===== Phase C: grouped GEMM over dynamic live tiles =====
    int lt0 = (c0 + BM - 1) / BM, lt1 = (c1 + BM - 1) / BM;
    int lt2 = (c2 + BM - 1) / BM, lt3 = (c3 + BM - 1) / BM;
    int lt4 = (c4 + BM - 1) / BM, lt5 = (c5 + BM - 1) / BM;
    int lt6 = (c6 + BM - 1) / BM, lt7 = (c7 + BM - 1) / BM;
    int s1 = lt0, s2 = s1 + lt1, s3 = s2 + lt2, s4 = s3 + lt3;
    int s5 = s4 + lt4, s6 = s5 + lt5, s7 = s6 + lt6, T = s7 + lt7;

    for (int w = blk; w < T; w += GRID) {
        int e, bse, cnt_e;
        if      (w < s1) { e = 0; bse = 0;  cnt_e = c0; }
        else if (w < s2) { e = 1; bse = s1; cnt_e = c1; }
        else if (w < s3) { e = 2; bse = s2; cnt_e = c2; }
        else if (w < s4) { e = 3; bse = s3; cnt_e = c3; }
        else if (w < s5) { e = 4; bse = s4; cnt_e = c4; }
        else if (w < s6) { e = 5; bse = s5; cnt_e = c5; }
        else if (w < s7) { e = 6; bse = s6; cnt_e = c6; }
        else             { e = 7; bse = s7; cnt_e = c7; }
        int rb   = (w - bse) * BM;
        int segc = cnt_e - rb;

        __syncthreads();   // previous iteration's xs readers done

        const unsigned short* xbt = xb + ((size_t)e * CAP + rb) * 256;
        #pragma unroll
        for (int it = 0; it < 8; ++it)
            gload_lds16(xbt + (size_t)it * 2048 + t * 8, &sm.c.xs[it * 2048 + wave * 512]);

        const unsigned short* w1pe = w1p + (size_t)e * (8 * 16 * 64 * 8);
        bf16x8 bcur[4];
        #pragma unroll
        for (int ni = 0; ni < 4; ++ni)
            bcur[ni] = *(const bf16x8*)&w1pe[(((wave * 4 + ni) * 64) + lane) * 8];

        {   // stage W2[e] (4KB) -> LDS padded
            const float* w2e = W2 + (size_t)e * HID * KM1;
            f32x4 wv = *(const f32x4*)(w2e + (size_t)t * 4);
            *(f32x4*)&sm.c.w2s[t * 4 + (t >> 6) * 4] = wv;
        }
        __syncthreads();   // xs (vmcnt drained) + w2s ready

        f32x4 acc[4][4];
        #pragma unroll
        for (int mi = 0; mi < 4; ++mi)
            #pragma unroll
            for (int ni = 0; ni < 4; ++ni) {
                f32x4 z = {0.f, 0.f, 0.f, 0.f};
                acc[mi][ni] = z;
            }

        #pragma unroll
        for (int ks = 0; ks < 8; ++ks) {
            bf16x8 bnext[4];
            if (ks < 7) {
                #pragma unroll
                for (int ni = 0; ni < 4; ++ni)
                    bnext[ni] = *(const bf16x8*)&w1pe[((((ks + 1) * 16 + wave * 4 + ni) * 64) + lane) * 8];
            }
            bf16x8 af[4];
            #pragma unroll
            for (int mi = 0; mi < 4; ++mi) {
                int r = mi * 16 + r15;
                af[mi] = *(const bf16x8*)&sm.c.xs[r * 256 + (SWZ(r, ks * 4 + hi) << 3)];
            }
            #pragma unroll
            for (int mi = 0; mi < 4; ++mi)
                #pragma unroll
                for (int ni = 0; ni < 4; ++ni)
                    acc[mi][ni] = __builtin_amdgcn_mfma_f32_16x16x32_bf16(
                        af[mi], bcur[ni], acc[mi][ni], 0, 0, 0);
            if (ks < 7) {
                #pragma unroll
                for (int ni = 0; ni < 4; ++ni) bcur[ni] = bnext[ni];
            }
        }
        __syncthreads();   // xs reads done before h overwrite

        float b1v[4];
        #pragma unroll
        for (int ni = 0; ni < 4; ++ni)
            b1v[ni] = b1[e * HID + wave * 64 + ni * 16 + r15];
        #pragma unroll
        for (int mi = 0; mi < 4; ++mi) {
            #pragma unroll
            for (int ni = 0; ni < 4; ++ni) {
                int colg  = wave * 64 + ni * 16 + r15;
                int chunk = colg >> 3;
                #pragma unroll
                for (int j = 0; j < 4; ++j) {
                    int rowg = mi * 16 + hi * 4 + j;
                    float h = fmaxf(acc[mi][ni][j] + b1v[ni], 0.f);
                    sm.c.xs[rowg * 256 + (SWZ(rowg, chunk) << 3) + (colg & 7)] = f2bf(h);
                }
            }
        }
        __syncthreads();

        int row = t >> 2, q = t & 3;
        f32x4 lac = {0.f, 0.f, 0.f, 0.f};
        #pragma unroll
        for (int s = 0; s < 8; ++s) {
            int c = q * 8 + s;
            u16x8 hv = *(const u16x8*)&sm.c.xs[row * 256 + (SWZ(row, c) << 3)];
            #pragma unroll
            for (int j = 0; j < 8; ++j) {
                int k = c * 8 + j;
                float hf = bf2f(hv[j]);
                const f32x4 wv = *(const f32x4*)&sm.c.w2s[k * 4 + (k >> 6) * 4];
                lac[0] += hf * wv[0]; lac[1] += hf * wv[1];
                lac[2] += hf * wv[2]; lac[3] += hf * wv[3];
            }
        }
        #pragma unroll
        for (int c4_ = 0; c4_ < 4; ++c4_) {
            lac[c4_] += __shfl_xor(lac[c4_], 1, 4);
            lac[c4_] += __shfl_xor(lac[c4_], 2, 4);
        }

        if (row < segc) {
            int smp = perm[(size_t)e * CAP + rb + row];
            const float* b2e = b2 + e * KM1;
            float l0 = lac[0] + b2e[0], l1 = lac[1] + b2e[1];
            float l2 = lac[2] + b2e[2], l3 = lac[3] + b2e[3];
            float q0 = 1.f / (1.f + expf(-l0)), q1v = 1.f / (1.f + expf(-l1));
            float q2v = 1.f / (1.f + expf(-l2)), q3v = 1.f / (1.f + expf(-l3));
            float p0 = fmaxf(1.f - q0, 1e-8f), p1 = fmaxf(q0 - q1v, 1e-8f);
            float p2 = fmaxf(q1v - q2v, 1e-8f), p3 = fmaxf(q2v - q3v, 1e-8f);
            float p4 = fmaxf(q3v, 1e-8f);
            float inv = 1.f / (p0 + p1 + p2 + p3 + p4);
            float myl = (q & 1) ? ((q & 2) ? l3 : l1) : ((q & 2) ? l2 : l0);
            float myp = (q & 1) ? ((q & 2) ? p3 : p1) : ((q & 2) ? p2 : p0);
            out[(size_t)smp * KM1 + q] = myl;
            float* probs = out + (size_t)B_N * KM1;
            probs[(size_t)smp * KCLS + q] = myp * inv;
            if (q == 3) probs[(size_t)smp * KCLS + 4] = p4 * inv;
        }
    }
}

// ======================= fallback pipeline (proven 33.8 µs, R4) =========
__global__ __launch_bounds__(256) void k_w1t(const float* __restrict__ W1,
                                             const int* __restrict__ sidx,
                                             unsigned short* __restrict__ w1p,
                                             int* __restrict__ part) {
    __shared__ float tile[64][65];
    __shared__ int wc[4][NE];
    int t = threadIdx.x, b = blockIdx.x;
    int lane = t & 63, wave = t >> 6;
    int es = sidx[b * 256 + t];
    #pragma unroll
    for (int t2 = 0; t2 < NE; ++t2) {
        unsigned long long m = __ballot(es == t2);
        if (lane == t2) wc[wave][t2] = (int)__popcll(m);
    }
    int e = b >> 4, ti = (b >> 2) & 3, th = b & 3;
    const float* src = W1 + (((size_t)e * INDIM) + (size_t)ti * 64) * HID + th * 64;
    int col = t & 63, r0 = (t >> 6) * 16;
    #pragma unroll
    for (int rr = 0; rr < 16; ++rr)
        tile[r0 + rr][col] = src[(size_t)(r0 + rr) * HID + col];
    __syncthreads();
    if (t < NE) part[b * NE + t] = wc[0][t] + wc[1][t] + wc[2][t] + wc[3][t];
    int u = t >> 6;
    #pragma unroll
    for (int ks2 = 0; ks2 < 2; ++ks2) {
        int ks = ti * 2 + ks2, nb = th * 4 + u;
        u16x8 v;
        #pragma unroll
        for (int j = 0; j < 8; ++j)
            v[j] = f2bf(tile[ks2 * 32 + (lane >> 4) * 8 + j][u * 16 + (lane & 15)]);
        *(u16x8*)&w1p[((((size_t)e * 8 + ks) * 16 + nb) * 64 + lane) * 8] = v;
    }
}

__global__ __launch_bounds__(256) void k_scatter(const int* __restrict__ sidx,
                                                 const int* __restrict__ part,
                                                 int* __restrict__ perm,
                                                 int* __restrict__ meta) {
    __shared__ int pp[128][NE];
    __shared__ int pre8[NE], tot8[NE];
    __shared__ int wc[4][NE];
    int t = threadIdx.x, b = blockIdx.x;
    int lane = t & 63, wave = t >> 6;
    if (t < 128) {
        #pragma unroll
        for (int e2 = 0; e2 < NE; ++e2) pp[t][e2] = part[t * NE + e2];
    }
    int i = b * 256 + t;
    int e = sidx[i];
    int posw = 0;
    #pragma unroll
    for (int t2 = 0; t2 < NE; ++t2) {
        unsigned long long m = __ballot(e == t2);
        if (e == t2) posw = (int)__popcll(m & ((1ull << lane) - 1ull));
        if (lane == t2) wc[wave][t2] = (int)__popcll(m);
    }
    __syncthreads();
    if (t < NE) {
        int s = 0, a = 0;
        for (int b2 = 0; b2 < 128; ++b2) {
            int v = pp[b2][t];
            if (b2 < b) s += v;
            a += v;
        }
        pre8[t] = s; tot8[t] = a;
        meta[t] = a;
    }
    __syncthreads();
    int off = 0;
    #pragma unroll
    for (int t2 = 0; t2 < NE; ++t2)
        off += (t2 < e) ? (((tot8[t2] + 63) >> 6) << 6) : 0;
    int wsum = 0;
    #pragma unroll
    for (int w2 = 0; w2 < 4; ++w2)
        wsum += (w2 < wave) ? wc[w2][e] : 0;
    perm[off + pre8[e] + wsum + posw] = i;
}

__global__ __launch_bounds__(256, 3) void k_main_fb(
    const float* __restrict__ x,  const float* __restrict__ b1,
    const float* __restrict__ W2, const float* __restrict__ b2,
    const unsigned short* __restrict__ w1p,
    const int* __restrict__ perm, const int* __restrict__ meta,
    float* __restrict__ out)
{
    __shared__ unsigned short xs[BM * 256];
    __shared__ float w2s[1040];
    int base = blockIdx.x * BM;
    int e = 0, segstart = 0, segcnt = 0, acc_off = 0;
    #pragma unroll
    for (int t = 0; t < NE; ++t) {
        int c  = meta[t];
        int st = acc_off;
        acc_off += ((c + 63) >> 6) << 6;
        if (base >= st) { e = t; segstart = st; segcnt = c; }
    }
    if (base >= acc_off) return;
    int segend = segstart + segcnt;

    int tid = threadIdx.x, lane = tid & 63, wave = tid >> 6;
    int r15 = lane & 15, hi = lane >> 4;

    const unsigned short* w1pe = w1p + (size_t)e * (8 * 16 * 64 * 8);
    auto loadB = [&](int ks, int ni) -> bf16x8 {
        return *(const bf16x8*)&w1pe[(((ks * 16 + wave * 4 + ni) * 64) + lane) * 8];
    };
    bf16x8 bcur[4];
    #pragma unroll
    for (int ni = 0; ni < 4; ++ni) bcur[ni] = loadB(0, ni);

    {
        int row  = tid & 63, q = tid >> 6;
        int prow = base + row;
        int smp  = (prow < segend) ? perm[prow] : -1;
        const float* xr = x + (size_t)(smp < 0 ? 0 : smp) * INDIM + q * 64;
        #pragma unroll
        for (int cc = 0; cc < 8; ++cc) {
            int csw = SWZ(row, q * 8 + cc);
            u16x8 v = {0, 0, 0, 0, 0, 0, 0, 0};
            if (smp >= 0) {
                const f32x4* p4 = (const f32x4*)(xr + cc * 8);
                f32x4 a0 = p4[0], a1 = p4[1];
                v[0] = f2bf(a0[0]); v[1] = f2bf(a0[1]); v[2] = f2bf(a0[2]); v[3] = f2bf(a0[3]);
                v[4] = f2bf(a1[0]); v[5] = f2bf(a1[1]); v[6] = f2bf(a1[2]); v[7] = f2bf(a1[3]);
            }
            *(u16x8*)&xs[row * 256 + (csw << 3)] = v;
        }
    }
    {
        const float* w2e = W2 + (size_t)e * HID * KM1;
        f32x4 wv = *(const f32x4*)(w2e + (size_t)tid * 4);
        *(f32x4*)&w2s[tid * 4 + (tid >> 6) * 4] = wv;
    }
    __syncthreads();

    f32x4 acc[4][4];
    #pragma unroll
    for (int mi = 0; mi < 4; ++mi)
        #pragma unroll
        for (int ni = 0; ni < 4; ++ni) {
            f32x4 z = {0.f, 0.f, 0.f, 0.f};
            acc[mi][ni] = z;
        }
    #pragma unroll
    for (int ks = 0; ks < 8; ++ks) {
        bf16x8 bnext[4];
        if (ks < 7) {
            #pragma unroll
            for (int ni = 0; ni < 4; ++ni) bnext[ni] = loadB(ks + 1, ni);
        }
        bf16x8 af[4];
        #pragma unroll
        for (int mi = 0; mi < 4; ++mi) {
            int r = mi * 16 + r15;
            af[mi] = *(const bf16x8*)&xs[r * 256 + (SWZ(r, ks * 4 + hi) << 3)];
        }
        #pragma unroll
        for (int mi = 0; mi < 4; ++mi)
            #pragma unroll
            for (int ni = 0; ni < 4; ++ni)
                acc[mi][ni] = __builtin_amdgcn_mfma_f32_16x16x32_bf16(
                    af[mi], bcur[ni], acc[mi][ni], 0, 0, 0);
        if (ks < 7) {
            #pragma unroll
            for (int ni = 0; ni < 4; ++ni) bcur[ni] = bnext[ni];
        }
    }
    __syncthreads();

    float b1v[4];
    #pragma unroll
    for (int ni = 0; ni < 4; ++ni)
        b1v[ni] = b1[e * HID + wave * 64 + ni * 16 + r15];
    #pragma unroll
    for (int mi = 0; mi < 4; ++mi) {
        #pragma unroll
        for (int ni = 0; ni < 4; ++ni) {
            int colg = wave * 64 + ni * 16 + r15;
            int chunk = colg >> 3;
            #pragma unroll
            for (int j = 0; j < 4; ++j) {
                int rowg = mi * 16 + hi * 4 + j;
                float h = fmaxf(acc[mi][ni][j] + b1v[ni], 0.f);
                xs[rowg * 256 + (SWZ(rowg, chunk) << 3) + (colg & 7)] = f2bf(h);
            }
        }
    }
    __syncthreads();

    int row = tid >> 2, q = tid & 3;
    f32x4 lac = {0.f, 0.f, 0.f, 0.f};
    #pragma unroll
    for (int s = 0; s < 8; ++s) {
        int c = q * 8 + s;
        u16x8 hv = *(const u16x8*)&xs[row * 256 + (SWZ(row, c) << 3)];
        #pragma unroll
        for (int j = 0; j < 8; ++j) {
            int k = c * 8 + j;
            float hf = bf2f(hv[j]);
            const f32x4 wv = *(const f32x4*)&w2s[k * 4 + (k >> 6) * 4];
            lac[0] += hf * wv[0]; lac[1] += hf * wv[1];
            lac[2] += hf * wv[2]; lac[3] += hf * wv[3];
        }
    }
    #pragma unroll
    for (int c4_ = 0; c4_ < 4; ++c4_) {
        lac[c4_] += __shfl_xor(lac[c4_], 1, 4);
        lac[c4_] += __shfl_xor(lac[c4_], 2, 4);
    }
    if (base + row < segend) {
        int smp = perm[base + row];
        const float* b2e = b2 + e * KM1;
        float l0 = lac[0] + b2e[0], l1 = lac[1] + b2e[1];
        float l2 = lac[2] + b2e[2], l3 = lac[3] + b2e[3];
        float q0 = 1.f / (1.f + expf(-l0)), q1v = 1.f / (1.f + expf(-l1));
        float q2v = 1.f / (1.f + expf(-l2)), q3v = 1.f / (1.f + expf(-l3));
        float p0 = fmaxf(1.f - q0, 1e-8f), p1 = fmaxf(q0 - q1v, 1e-8f);
        float p2 = fmaxf(q1v - q2v, 1e-8f), p3 = fmaxf(q2v - q3v, 1e-8f);
        float p4 = fmaxf(q3v, 1e-8f);
        float inv = 1.f / (p0 + p1 + p2 + p3 + p4);
        float myl = (q & 1) ? ((q & 2) ? l3 : l1) : ((q & 2) ? l2 : l0);
        float myp = (q & 1) ? ((q & 2) ? p3 : p1) : ((q & 2) ? p2 : p0);
        out[(size_t)smp * KM1 + q] = myl;
        float* probs = out + (size_t)B_N * KM1;
        probs[(size_t)smp * KCLS + q] = myp * inv;
        if (q == 3) probs[(size_t)smp * KCLS + 4] = p4 * inv;
    }
}

extern "C" void kernel_launch(void* const* d_in, const int* in_sizes, int n_in,
                              void* d_out, int out_size, void* d_ws, size_t ws_size,
                              hipStream_t stream) {
    const float* x   = (const float*)d_in[0];
    const int*   sid = (const int*)d_in[1];
    const float* W1  = (const float*)d_in[2];
    const float* b1  = (const float*)d_in[3];
    const float* W2  = (const float*)d_in[4];
    const float* b2  = (const float*)d_in[5];
    float* out = (float*)d_out;

    char* ws = (char*)d_ws;
    unsigned short* w1p = (unsigned short*)ws;                   // 1 MB
    unsigned short* xb  = (unsigned short*)(ws + 1048576);       // 32 MB (coop)
    int* perm  = (int*)(ws + 34603008);                          // 256 KB (both)
    int* wpart = (int*)(ws + 34865152);                          // 16 KB (coop)
    int* part  = (int*)(ws + 34881536);                          // 4 KB (fallback)
    int* meta  = (int*)(ws + 34889728);                          // 32 B (fallback)

    void* args[] = { (void*)&x, (void*)&sid, (void*)&W1, (void*)&b1,
                     (void*)&W2, (void*)&b2, (void*)&w1p, (void*)&xb,
                     (void*)&perm, (void*)&wpart, (void*)&out };
    hipError_t err = hipLaunchCooperativeKernel((void*)k_all, dim3(GRID),
                                                dim3(256), args, 0, stream);
    if (err != hipSuccess) {
        // cooperative unsupported/too large -> proven 3-kernel pipeline
        k_w1t    <<<dim3(128),     dim3(256), 0, stream>>>(W1, sid, w1p, part);
        k_scatter<<<dim3(128),     dim3(256), 0, stream>>>(sid, part, perm, meta);
        k_main_fb<<<dim3(NBLK_FB), dim3(256), 0, stream>>>(x, b1, W2, b2, w1p, perm, meta, out);
    }
}

// Round 12
// 57.536 us; speedup vs baseline: 5.0112x; 5.0112x over previous
//
#include <hip/hip_runtime.h>
#include <stdint.h>
#include <math.h>

// Problem constants (match reference)
#define B_N   32768
#define INDIM 256
#define HID   256
#define NE    8
#define KM1   4
#define KCLS  5
#define BM    64
#define CAP   8192
#define GRID_P 256          // k_prep blocks (co-residency: need 1/CU, have 6/CU)
#define SPB   128           // samples per k_prep block
#define TPE   (CAP / BM)
#define NBLK  (NE * TPE)    // 1024 k_main blocks

typedef __bf16 bf16x8 __attribute__((ext_vector_type(8)));
typedef float  f32x4  __attribute__((ext_vector_type(4)));
typedef unsigned short u16x8 __attribute__((ext_vector_type(8)));

__device__ __forceinline__ unsigned short f2bf(float f) {
    union { float f; unsigned u; } v; v.f = f;
    unsigned r = v.u + 0x7FFFu + ((v.u >> 16) & 1u);   // RNE
    return (unsigned short)(r >> 16);
}
__device__ __forceinline__ float bf2f(unsigned short b) {
    union { unsigned u; float f; } v; v.u = ((unsigned)b) << 16;
    return v.f;
}
// chunk-of-8-bf16 swizzle (bank-verified): slot = chunk ^ (row&7)
__device__ __forceinline__ int SWZ(int r, int c) { return c ^ (r & 7); }

__device__ __forceinline__ void gload_lds16(const void* g, void* l) {
    __builtin_amdgcn_global_load_lds(
        (__attribute__((address_space(1))) unsigned int*)(g),
        (__attribute__((address_space(3))) unsigned int*)(l),
        16, 0, 0);
}

// ==== k_prep: histogram -> spin grid-barrier -> prefix+rank -> convert ====
// 256 blocks x 256 threads, guaranteed co-resident (26KB LDS, 1 needed of 6/CU).
// Cross-XCD visibility via agent-scope atomics (per Guideline 16).
__global__ __launch_bounds__(256) void k_prep(
    const float* __restrict__ W1, const float* __restrict__ x,
    const int* __restrict__ sidx,
    unsigned short* __restrict__ w1p, unsigned short* __restrict__ xb,
    int* __restrict__ perm, int* __restrict__ wpart,
    int* __restrict__ meta, int* __restrict__ done)
{
    __shared__ float tile[64][65];      // W1 pack staging (blocks < 128)
    __shared__ int   pp[NE][260];       // transposed partials
    __shared__ int   pr[8][NE][2];
    __shared__ int   pre8[NE], tot8[NE];
    __shared__ int   wc01[2][NE];
    __shared__ int   posbuf[SPB];

    int t    = threadIdx.x;
    int blk  = blockIdx.x;
    int lane = t & 63;
    int wave = t >> 6;

    // (1) histogram own 128 samples (waves 0,1 fully active)
    int mye = -1, posw = 0;
    if (t < SPB) {
        mye = sidx[blk * SPB + t];
        #pragma unroll
        for (int t2 = 0; t2 < NE; ++t2) {
            unsigned long long m = __ballot(mye == t2);
            if (mye == t2) posw = (int)__popcll(m & ((1ull << lane) - 1ull));
            if (lane == t2) wc01[wave][t2] = (int)__popcll(m);
        }
    }
    __syncthreads();

    // (2) publish partials (agent-scope release) + signal arrival
    if (t < NE)
        __hip_atomic_store(&wpart[blk * NE + t], wc01[0][t] + wc01[1][t],
                           __ATOMIC_RELEASE, __HIP_MEMORY_SCOPE_AGENT);
    __syncthreads();
    if (t == 0)
        __hip_atomic_fetch_add(done, 1, __ATOMIC_RELEASE, __HIP_MEMORY_SCOPE_AGENT);

    // (3) W1 pack (blocks < 128) — overlaps other blocks' arrival
    if (blk < 128) {
        int e = blk >> 4, ti = (blk >> 2) & 3, th = blk & 3;
        const float* src = W1 + (((size_t)e * INDIM) + (size_t)ti * 64) * HID + th * 64;
        int col = t & 63, r0 = (t >> 6) * 16;
        #pragma unroll
        for (int rr = 0; rr < 16; ++rr)
            tile[r0 + rr][col] = src[(size_t)(r0 + rr) * HID + col];
        __syncthreads();
        int u = t >> 6;
        #pragma unroll
        for (int ks2 = 0; ks2 < 2; ++ks2) {
            int ks = ti * 2 + ks2, nb = th * 4 + u;
            u16x8 v;
            #pragma unroll
            for (int j = 0; j < 8; ++j)
                v[j] = f2bf(tile[ks2 * 32 + (lane >> 4) * 8 + j][u * 16 + (lane & 15)]);
            *(u16x8*)&w1p[((((size_t)e * 8 + ks) * 16 + nb) * 64 + lane) * 8] = v;
        }
    }

    // (4) spin barrier: all 256 blocks co-resident by construction
    if (t == 0) {
        while (__hip_atomic_load(done, __ATOMIC_ACQUIRE,
                                 __HIP_MEMORY_SCOPE_AGENT) < GRID_P)
            __builtin_amdgcn_s_sleep(2);
    }
    __syncthreads();

    // (5) load all partials (agent-scope: bypass non-coherent local L2)
    {
        #pragma unroll
        for (int i = 0; i < NE; ++i)
            pp[i][t] = __hip_atomic_load(&wpart[t * NE + i], __ATOMIC_RELAXED,
                                         __HIP_MEMORY_SCOPE_AGENT);
    }
    __syncthreads();

    // (6) prefix: 64 threads, expert t&7, range t>>3 covers 32 chunks
    if (t < 64) {
        int e2 = t & 7, r = t >> 3;
        int sb = 0, sa = 0;
        #pragma unroll
        for (int c = 0; c < 32; ++c) {
            int ch = r * 32 + c;
            int v  = pp[e2][ch];
            sa += v; sb += (ch < blk) ? v : 0;
        }
        pr[r][e2][0] = sb; pr[r][e2][1] = sa;
    }
    __syncthreads();
    if (t < NE) {
        int sb = 0, sa = 0;
        #pragma unroll
        for (int r = 0; r < 8; ++r) { sb += pr[r][t][0]; sa += pr[r][t][1]; }
        pre8[t] = sb; tot8[t] = sa;
        meta[t] = sa;                      // identical from every block: benign
    }
    __syncthreads();

    // (7) rank own samples -> perm, posbuf
    if (t < SPB) {
        int rank = pre8[mye] + ((wave == 1) ? wc01[0][mye] : 0) + posw;
        int pos  = mye * CAP + rank;
        posbuf[t] = pos;
        perm[pos] = blk * SPB + t;
    }
    __syncthreads();

    // (8) convert+scatter 128 rows -> xb (pre-swizzled bf16); 2 threads/row
    {
        int si  = t & 127, h = t >> 7;
        int pos = posbuf[si];
        int r   = pos & (BM - 1);
        const float* xr = x + (size_t)(blk * SPB + si) * INDIM + h * 128;
        unsigned short* dst = xb + (size_t)pos * 256;
        #pragma unroll
        for (int cc = 0; cc < 16; ++cc) {
            int ch = h * 16 + cc;
            f32x4 a0 = *(const f32x4*)(xr + cc * 8);
            f32x4 a1 = *(const f32x4*)(xr + cc * 8 + 4);
            u16x8 v;
            v[0] = f2bf(a0[0]); v[1] = f2bf(a0[1]); v[2] = f2bf(a0[2]); v[3] = f2bf(a0[3]);
            v[4] = f2bf(a1[0]); v[5] = f2bf(a1[1]); v[6] = f2bf(a1[2]); v[7] = f2bf(a1[3]);
            *(u16x8*)&dst[SWZ(r, ch) * 8] = v;
        }
    }
}

// ==== k_main: grouped GEMM from pre-staged xb; B from XCD-local L2 (R9, proven) ====
__global__ __launch_bounds__(256, 4) void k_main(
    const float* __restrict__ b1, const float* __restrict__ W2,
    const float* __restrict__ b2,
    const unsigned short* __restrict__ w1p,
    const unsigned short* __restrict__ xb,
    const int* __restrict__ perm, const int* __restrict__ meta,
    float* __restrict__ out)
{
    __shared__ unsigned short xs[BM * 256];
    __shared__ float w2s[1040];

    int bid = (blockIdx.x & 7) * TPE + (blockIdx.x >> 3);
    int e   = bid >> 7;
    int tl  = bid & (TPE - 1);
    int cnt = meta[e];
    int rb  = tl * BM;
    if (rb >= cnt) return;
    int segc = cnt - rb;

    int tid  = threadIdx.x;
    int lane = tid & 63;
    int wave = tid >> 6;
    int r15  = lane & 15;
    int hi   = lane >> 4;

    const unsigned short* xbt = xb + ((size_t)e * CAP + rb) * 256;
    #pragma unroll
    for (int it = 0; it < 8; ++it)
        gload_lds16(xbt + ((size_t)it * 256 + tid) * 8, &xs[it * 2048 + wave * 512]);

    const unsigned short* w1pe = w1p + (size_t)e * (8 * 16 * 64 * 8);
    auto loadB = [&](int ks, int ni) -> bf16x8 {
        return *(const bf16x8*)&w1pe[(((ks * 16 + wave * 4 + ni) * 64) + lane) * 8];
    };
    bf16x8 bcur[4];
    #pragma unroll
    for (int ni = 0; ni < 4; ++ni) bcur[ni] = loadB(0, ni);

    {
        const float* w2e = W2 + (size_t)e * HID * KM1;
        f32x4 wv = *(const f32x4*)(w2e + (size_t)tid * 4);
        *(f32x4*)&w2s[tid * 4 + (tid >> 6) * 4] = wv;
    }
    __syncthreads();

    f32x4 acc[4][4];
    #pragma unroll
    for (int mi = 0; mi < 4; ++mi)
        #pragma unroll
        for (int ni = 0; ni < 4; ++ni) {
            f32x4 z = {0.f, 0.f, 0.f, 0.f};
            acc[mi][ni] = z;
        }

    #pragma unroll
    for (int ks = 0; ks < 8; ++ks) {
        bf16x8 bnext[4];
        if (ks < 7) {
            #pragma unroll
            for (int ni = 0; ni < 4; ++ni) bnext[ni] = loadB(ks + 1, ni);
        }
        bf16x8 af[4];
        #pragma unroll
        for (int mi = 0; mi < 4; ++mi) {
            int r = mi * 16 + r15;
            af[mi] = *(const bf16x8*)&xs[r * 256 + (SWZ(r, ks * 4 + hi) << 3)];
        }
        #pragma unroll
        for (int mi = 0; mi < 4; ++mi)
            #pragma unroll
            for (int ni = 0; ni < 4; ++ni)
                acc[mi][ni] = __builtin_amdgcn_mfma_f32_16x16x32_bf16(
                    af[mi], bcur[ni], acc[mi][ni], 0, 0, 0);
        if (ks < 7) {
            #pragma unroll
            for (int ni = 0; ni < 4; ++ni) bcur[ni] = bnext[ni];
        }
    }
    __syncthreads();

    float b1v[4];
    #pragma unroll
    for (int ni = 0; ni < 4; ++ni)
        b1v[ni] = b1[e * HID + wave * 64 + ni * 16 + r15];
    #pragma unroll
    for (int mi = 0; mi < 4; ++mi) {
        #pragma unroll
        for (int ni = 0; ni < 4; ++ni) {
            int colg  = wave * 64 + ni * 16 + r15;
            int chunk = colg >> 3;
            #pragma unroll
            for (int j = 0; j < 4; ++j) {
                int rowg = mi * 16 + hi * 4 + j;
                float h = fmaxf(acc[mi][ni][j] + b1v[ni], 0.f);
                xs[rowg * 256 + (SWZ(rowg, chunk) << 3) + (colg & 7)] = f2bf(h);
            }
        }
    }
    __syncthreads();

    int row = tid >> 2, q = tid & 3;
    f32x4 lac = {0.f, 0.f, 0.f, 0.f};
    #pragma unroll
    for (int s = 0; s < 8; ++s) {
        int c = q * 8 + s;
        u16x8 hv = *(const u16x8*)&xs[row * 256 + (SWZ(row, c) << 3)];
        #pragma unroll
        for (int j = 0; j < 8; ++j) {
            int k = c * 8 + j;
            float hf = bf2f(hv[j]);
            const f32x4 wv = *(const f32x4*)&w2s[k * 4 + (k >> 6) * 4];
            lac[0] += hf * wv[0]; lac[1] += hf * wv[1];
            lac[2] += hf * wv[2]; lac[3] += hf * wv[3];
        }
    }
    #pragma unroll
    for (int c4_ = 0; c4_ < 4; ++c4_) {
        lac[c4_] += __shfl_xor(lac[c4_], 1, 4);
        lac[c4_] += __shfl_xor(lac[c4_], 2, 4);
    }

    if (row < segc) {
        int smp = perm[(size_t)e * CAP + rb + row];
        const float* b2e = b2 + e * KM1;
        float l0 = lac[0] + b2e[0], l1 = lac[1] + b2e[1];
        float l2 = lac[2] + b2e[2], l3 = lac[3] + b2e[3];
        float q0 = 1.f / (1.f + expf(-l0)), q1v = 1.f / (1.f + expf(-l1));
        float q2v = 1.f / (1.f + expf(-l2)), q3v = 1.f / (1.f + expf(-l3));
        float p0 = fmaxf(1.f - q0, 1e-8f), p1 = fmaxf(q0 - q1v, 1e-8f);
        float p2 = fmaxf(q1v - q2v, 1e-8f), p3 = fmaxf(q2v - q3v, 1e-8f);
        float p4 = fmaxf(q3v, 1e-8f);
        float inv = 1.f / (p0 + p1 + p2 + p3 + p4);
        float myl = (q & 1) ? ((q & 2) ? l3 : l1) : ((q & 2) ? l2 : l0);
        float myp = (q & 1) ? ((q & 2) ? p3 : p1) : ((q & 2) ? p2 : p0);
        out[(size_t)smp * KM1 + q] = myl;
        float* probs = out + (size_t)B_N * KM1;
        probs[(size_t)smp * KCLS + q] = myp * inv;
        if (q == 3) probs[(size_t)smp * KCLS + 4] = p4 * inv;
    }
}

extern "C" void kernel_launch(void* const* d_in, const int* in_sizes, int n_in,
                              void* d_out, int out_size, void* d_ws, size_t ws_size,
                              hipStream_t stream) {
    const float* x   = (const float*)d_in[0];
    const int*   sid = (const int*)d_in[1];
    const float* W1  = (const float*)d_in[2];
    const float* b1  = (const float*)d_in[3];
    const float* W2  = (const float*)d_in[4];
    const float* b2  = (const float*)d_in[5];
    float* out = (float*)d_out;

    char* ws = (char*)d_ws;
    unsigned short* w1p = (unsigned short*)ws;                   // 1 MB
    unsigned short* xb  = (unsigned short*)(ws + 1048576);       // 32 MB
    int* perm  = (int*)(ws + 34603008);                          // 256 KB
    int* wpart = (int*)(ws + 34865152);                          // 8 KB
    int* meta  = (int*)(ws + 34873600);                          // 32 B
    int* done  = (int*)(ws + 34873664);                          // 4 B

    hipMemsetAsync(done, 0, 4, stream);
    k_prep<<<dim3(GRID_P), dim3(256), 0, stream>>>(W1, x, sid, w1p, xb,
                                                   perm, wpart, meta, done);
    k_main<<<dim3(NBLK),   dim3(256), 0, stream>>>(b1, W2, b2, w1p, xb,
                                                   perm, meta, out);
}

// Round 13
// 38.853 us; speedup vs baseline: 7.4211x; 1.4809x over previous
//
#include <hip/hip_runtime.h>
#include <stdint.h>
#include <math.h>

// Problem constants (match reference)
#define B_N   32768
#define INDIM 256
#define HID   256
#define NE    8
#define KM1   4
#define KCLS  5
#define BM    64
#define CAP   8192
#define TPE   (CAP / BM)
#define NBLK  (NE * TPE)    // 1024 k_main blocks

typedef __bf16 bf16x8 __attribute__((ext_vector_type(8)));
typedef float  f32x4  __attribute__((ext_vector_type(4)));
typedef unsigned short u16x8 __attribute__((ext_vector_type(8)));

// native cast -> compiler emits v_cvt_pk_bf16_f32 pairs (RNE), ~6x fewer VALU
__device__ __forceinline__ unsigned short f2bf(float f) {
    union { __bf16 h; unsigned short u; } v;
    v.h = (__bf16)f;
    return v.u;
}
__device__ __forceinline__ float bf2f(unsigned short b) {
    union { unsigned u; float f; } v; v.u = ((unsigned)b) << 16;
    return v.f;
}
// chunk-of-8-bf16 swizzle (bank-verified): slot = chunk ^ (row&7)
__device__ __forceinline__ int SWZ(int r, int c) { return c ^ (r & 7); }

__device__ __forceinline__ void gload_lds16(const void* g, void* l) {
    __builtin_amdgcn_global_load_lds(
        (__attribute__((address_space(1))) unsigned int*)(g),
        (__attribute__((address_space(3))) unsigned int*)(l),
        16, 0, 0);
}

// ==== prep 1: W1 pack + per-128-sample histogram partials (plain stores) ====
// 128 blocks x 256 threads.
__global__ __launch_bounds__(256) void k_w1t(const float* __restrict__ W1,
                                             const int* __restrict__ sidx,
                                             unsigned short* __restrict__ w1p,
                                             int* __restrict__ part) {
    __shared__ float tile[64][65];
    __shared__ int wc[4][NE];
    int t    = threadIdx.x;
    int b    = blockIdx.x;
    int lane = t & 63;
    int wave = t >> 6;

    int es = sidx[b * 256 + t];
    #pragma unroll
    for (int t2 = 0; t2 < NE; ++t2) {
        unsigned long long m = __ballot(es == t2);
        if (lane == t2) wc[wave][t2] = (int)__popcll(m);
    }

    int e = b >> 4, ti = (b >> 2) & 3, th = b & 3;
    const float* src = W1 + (((size_t)e * INDIM) + (size_t)ti * 64) * HID + th * 64;
    int col = t & 63, r0 = (t >> 6) * 16;
    #pragma unroll
    for (int rr = 0; rr < 16; ++rr)
        tile[r0 + rr][col] = src[(size_t)(r0 + rr) * HID + col];
    __syncthreads();

    if (t < NE) {
        part[(2 * b) * NE + t]     = wc[0][t] + wc[1][t];
        part[(2 * b + 1) * NE + t] = wc[2][t] + wc[3][t];
    }

    int u = t >> 6;
    #pragma unroll
    for (int ks2 = 0; ks2 < 2; ++ks2) {
        int ks = ti * 2 + ks2, nb = th * 4 + u;
        u16x8 v;
        #pragma unroll
        for (int j = 0; j < 8; ++j)
            v[j] = f2bf(tile[ks2 * 32 + (lane >> 4) * 8 + j][u * 16 + (lane & 15)]);
        *(u16x8*)&w1p[((((size_t)e * 8 + ks) * 16 + nb) * 64 + lane) * 8] = v;
    }
}

// ==== prep 2: rank + convert/scatter, 1024 blocks (4/CU) ====
// Blocks in groups of 4 share chunk c = blk>>2 (128 samples): all 4 redundantly
// prefix+rank (cheap); each converts 32 of the 128 rows (4x convert occupancy).
__global__ __launch_bounds__(256) void k_rankconv(
    const float* __restrict__ x, const int* __restrict__ sidx,
    const int* __restrict__ part,
    unsigned short* __restrict__ xb, int* __restrict__ perm,
    int* __restrict__ meta)
{
    __shared__ int pp[NE][260];     // transposed partials (pad)
    __shared__ int pr[8][NE][2];
    __shared__ int pre8[NE], tot8[NE], wc0[NE];
    __shared__ int posbuf[128];

    int t    = threadIdx.x;
    int c    = blockIdx.x >> 2;     // 128-sample chunk id (0..255)
    int sub  = blockIdx.x & 3;      // which quarter of the chunk to convert
    int lane = t & 63;
    int wave = t >> 6;

    // load partials: part[chunk][e] -> pp[e][chunk] (each thread 32B)
    #pragma unroll
    for (int e2 = 0; e2 < NE; ++e2) pp[e2][t] = part[t * NE + e2];

    // rank chunk's 128 samples (waves 0,1 fully active)
    int mye = 0, posw = 0;
    if (t < 128) {
        mye = sidx[c * 128 + t];
        #pragma unroll
        for (int t2 = 0; t2 < NE; ++t2) {
            unsigned long long m = __ballot(mye == t2);
            if (mye == t2) posw = (int)__popcll(m & ((1ull << lane) - 1ull));
            if (wave == 0 && lane == t2) wc0[t2] = (int)__popcll(m);
        }
    }
    __syncthreads();

    // prefix: 64 threads, expert t&7, range t>>3 covers 32 chunks
    if (t < 64) {
        int e2 = t & 7, r = t >> 3;
        int sb = 0, sa = 0;
        #pragma unroll
        for (int ch0 = 0; ch0 < 32; ++ch0) {
            int ch = r * 32 + ch0;
            int v  = pp[e2][ch];
            sa += v; sb += (ch < c) ? v : 0;
        }
        pr[r][e2][0] = sb; pr[r][e2][1] = sa;
    }
    __syncthreads();
    if (t < NE) {
        int sb = 0, sa = 0;
        #pragma unroll
        for (int r = 0; r < 8; ++r) { sb += pr[r][t][0]; sa += pr[r][t][1]; }
        pre8[t] = sb; tot8[t] = sa;
        meta[t] = sa;                  // identical value from every block: benign
    }
    __syncthreads();

    if (t < 128) {
        int rank = pre8[mye] + ((wave == 1) ? wc0[mye] : 0) + posw;
        int pos  = mye * CAP + rank;
        posbuf[t] = pos;
        if (sub == 0) perm[pos] = c * 128 + t;
    }
    __syncthreads();

    // convert rows [sub*32, sub*32+32): 8 threads/row, 32 floats each
    {
        int rloc = sub * 32 + (t >> 3);
        int seg  = t & 7;
        int pos  = posbuf[rloc];
        int r    = pos & (BM - 1);
        const float* xr = x + (size_t)(c * 128 + rloc) * INDIM + seg * 32;
        unsigned short* dst = xb + (size_t)pos * 256;
        #pragma unroll
        for (int cc = 0; cc < 4; ++cc) {
            int ch = seg * 4 + cc;
            f32x4 a0 = *(const f32x4*)(xr + cc * 8);
            f32x4 a1 = *(const f32x4*)(xr + cc * 8 + 4);
            u16x8 v;
            v[0] = f2bf(a0[0]); v[1] = f2bf(a0[1]); v[2] = f2bf(a0[2]); v[3] = f2bf(a0[3]);
            v[4] = f2bf(a1[0]); v[5] = f2bf(a1[1]); v[6] = f2bf(a1[2]); v[7] = f2bf(a1[3]);
            *(u16x8*)&dst[SWZ(r, ch) * 8] = v;
        }
    }
}

// ==== k_main: grouped GEMM from pre-staged xb; B from XCD-local L2 (proven) ====
__global__ __launch_bounds__(256, 4) void k_main(
    const float* __restrict__ b1, const float* __restrict__ W2,
    const float* __restrict__ b2,
    const unsigned short* __restrict__ w1p,
    const unsigned short* __restrict__ xb,
    const int* __restrict__ perm, const int* __restrict__ meta,
    float* __restrict__ out)
{
    __shared__ unsigned short xs[BM * 256];
    __shared__ float w2s[1040];

    int bid = (blockIdx.x & 7) * TPE + (blockIdx.x >> 3);
    int e   = bid >> 7;
    int tl  = bid & (TPE - 1);
    int cnt = meta[e];
    int rb  = tl * BM;
    if (rb >= cnt) return;
    int segc = cnt - rb;

    int tid  = threadIdx.x;
    int lane = tid & 63;
    int wave = tid >> 6;
    int r15  = lane & 15;
    int hi   = lane >> 4;

    const unsigned short* xbt = xb + ((size_t)e * CAP + rb) * 256;
    #pragma unroll
    for (int it = 0; it < 8; ++it)
        gload_lds16(xbt + ((size_t)it * 256 + tid) * 8, &xs[it * 2048 + wave * 512]);

    const unsigned short* w1pe = w1p + (size_t)e * (8 * 16 * 64 * 8);
    auto loadB = [&](int ks, int ni) -> bf16x8 {
        return *(const bf16x8*)&w1pe[(((ks * 16 + wave * 4 + ni) * 64) + lane) * 8];
    };
    bf16x8 bcur[4];
    #pragma unroll
    for (int ni = 0; ni < 4; ++ni) bcur[ni] = loadB(0, ni);

    {
        const float* w2e = W2 + (size_t)e * HID * KM1;
        f32x4 wv = *(const f32x4*)(w2e + (size_t)tid * 4);
        *(f32x4*)&w2s[tid * 4 + (tid >> 6) * 4] = wv;
    }
    __syncthreads();

    f32x4 acc[4][4];
    #pragma unroll
    for (int mi = 0; mi < 4; ++mi)
        #pragma unroll
        for (int ni = 0; ni < 4; ++ni) {
            f32x4 z = {0.f, 0.f, 0.f, 0.f};
            acc[mi][ni] = z;
        }

    #pragma unroll
    for (int ks = 0; ks < 8; ++ks) {
        bf16x8 bnext[4];
        if (ks < 7) {
            #pragma unroll
            for (int ni = 0; ni < 4; ++ni) bnext[ni] = loadB(ks + 1, ni);
        }
        bf16x8 af[4];
        #pragma unroll
        for (int mi = 0; mi < 4; ++mi) {
            int r = mi * 16 + r15;
            af[mi] = *(const bf16x8*)&xs[r * 256 + (SWZ(r, ks * 4 + hi) << 3)];
        }
        #pragma unroll
        for (int mi = 0; mi < 4; ++mi)
            #pragma unroll
            for (int ni = 0; ni < 4; ++ni)
                acc[mi][ni] = __builtin_amdgcn_mfma_f32_16x16x32_bf16(
                    af[mi], bcur[ni], acc[mi][ni], 0, 0, 0);
        if (ks < 7) {
            #pragma unroll
            for (int ni = 0; ni < 4; ++ni) bcur[ni] = bnext[ni];
        }
    }
    __syncthreads();

    float b1v[4];
    #pragma unroll
    for (int ni = 0; ni < 4; ++ni)
        b1v[ni] = b1[e * HID + wave * 64 + ni * 16 + r15];
    #pragma unroll
    for (int mi = 0; mi < 4; ++mi) {
        #pragma unroll
        for (int ni = 0; ni < 4; ++ni) {
            int colg  = wave * 64 + ni * 16 + r15;
            int chunk = colg >> 3;
            #pragma unroll
            for (int j = 0; j < 4; ++j) {
                int rowg = mi * 16 + hi * 4 + j;
                float h = fmaxf(acc[mi][ni][j] + b1v[ni], 0.f);
                xs[rowg * 256 + (SWZ(rowg, chunk) << 3) + (colg & 7)] = f2bf(h);
            }
        }
    }
    __syncthreads();

    int row = tid >> 2, q = tid & 3;
    f32x4 lac = {0.f, 0.f, 0.f, 0.f};
    #pragma unroll
    for (int s = 0; s < 8; ++s) {
        int c = q * 8 + s;
        u16x8 hv = *(const u16x8*)&xs[row * 256 + (SWZ(row, c) << 3)];
        #pragma unroll
        for (int j = 0; j < 8; ++j) {
            int k = c * 8 + j;
            float hf = bf2f(hv[j]);
            const f32x4 wv = *(const f32x4*)&w2s[k * 4 + (k >> 6) * 4];
            lac[0] += hf * wv[0]; lac[1] += hf * wv[1];
            lac[2] += hf * wv[2]; lac[3] += hf * wv[3];
        }
    }
    #pragma unroll
    for (int c4_ = 0; c4_ < 4; ++c4_) {
        lac[c4_] += __shfl_xor(lac[c4_], 1, 4);
        lac[c4_] += __shfl_xor(lac[c4_], 2, 4);
    }

    if (row < segc) {
        int smp = perm[(size_t)e * CAP + rb + row];
        const float* b2e = b2 + e * KM1;
        float l0 = lac[0] + b2e[0], l1 = lac[1] + b2e[1];
        float l2 = lac[2] + b2e[2], l3 = lac[3] + b2e[3];
        float q0 = 1.f / (1.f + expf(-l0)), q1v = 1.f / (1.f + expf(-l1));
        float q2v = 1.f / (1.f + expf(-l2)), q3v = 1.f / (1.f + expf(-l3));
        float p0 = fmaxf(1.f - q0, 1e-8f), p1 = fmaxf(q0 - q1v, 1e-8f);
        float p2 = fmaxf(q1v - q2v, 1e-8f), p3 = fmaxf(q2v - q3v, 1e-8f);
        float p4 = fmaxf(q3v, 1e-8f);
        float inv = 1.f / (p0 + p1 + p2 + p3 + p4);
        float myl = (q & 1) ? ((q & 2) ? l3 : l1) : ((q & 2) ? l2 : l0);
        float myp = (q & 1) ? ((q & 2) ? p3 : p1) : ((q & 2) ? p2 : p0);
        out[(size_t)smp * KM1 + q] = myl;
        float* probs = out + (size_t)B_N * KM1;
        probs[(size_t)smp * KCLS + q] = myp * inv;
        if (q == 3) probs[(size_t)smp * KCLS + 4] = p4 * inv;
    }
}

extern "C" void kernel_launch(void* const* d_in, const int* in_sizes, int n_in,
                              void* d_out, int out_size, void* d_ws, size_t ws_size,
                              hipStream_t stream) {
    const float* x   = (const float*)d_in[0];
    const int*   sid = (const int*)d_in[1];
    const float* W1  = (const float*)d_in[2];
    const float* b1  = (const float*)d_in[3];
    const float* W2  = (const float*)d_in[4];
    const float* b2  = (const float*)d_in[5];
    float* out = (float*)d_out;

    char* ws = (char*)d_ws;
    unsigned short* w1p = (unsigned short*)ws;                   // 1 MB
    unsigned short* xb  = (unsigned short*)(ws + 1048576);       // 32 MB
    int* perm = (int*)(ws + 34603008);                           // 256 KB
    int* part = (int*)(ws + 34865152);                           // 8 KB
    int* meta = (int*)(ws + 34873600);                           // 32 B

    k_w1t     <<<dim3(128),  dim3(256), 0, stream>>>(W1, sid, w1p, part);
    k_rankconv<<<dim3(1024), dim3(256), 0, stream>>>(x, sid, part, xb, perm, meta);
    k_main    <<<dim3(NBLK), dim3(256), 0, stream>>>(b1, W2, b2, w1p, xb, perm, meta, out);
}